// Round 7
// baseline (731.728 us; speedup 1.0000x reference)
//
#include <hip/hip_runtime.h>
#include <hip/hip_bf16.h>
#include <hip/hip_fp8.h>
#include <cstdint>

typedef __hip_bfloat16 bf16;
typedef __bf16 b8 __attribute__((ext_vector_type(8)));
typedef float f4v __attribute__((ext_vector_type(4)));
typedef short s8v __attribute__((ext_vector_type(8)));
typedef int i8v __attribute__((ext_vector_type(8)));

#define DEVI static __device__ __forceinline__

// async global->LDS, 16B per lane. LDS dest is wave-uniform base + lane*16.
DEVI void gload16(const void* g, void* l) {
  __builtin_amdgcn_global_load_lds(
      (const __attribute__((address_space(1))) void*)(uintptr_t)g,
      (__attribute__((address_space(3))) void*)(uint32_t)(uintptr_t)l,
      16, 0, 0);
}

DEVI f4v mfma_bf16(b8 a, b8 b, f4v c) {
  return __builtin_amdgcn_mfma_f32_16x16x32_bf16(a, b, c, 0, 0, 0);
}

// MX-scaled fp8 (OCP e4m3), K=128, unit scales (E8M0 127 = 2^0 in every byte).
DEVI f4v mfma_fp8(i8v a, i8v b, f4v c) {
  return __builtin_amdgcn_mfma_scale_f32_16x16x128_f8f6f4(
      a, b, c, 0, 0, 0, 0x7F7F7F7F, 0, 0x7F7F7F7F);
}

DEVI uint8_t to_fp8(float f) {
  __hip_fp8_e4m3 v(f);
  return v.__x;
}

// ---------------------------------------------------------------------------
// prep: x -> cur (fp32) + curb (bf16) + curf8 (fp8 e4m3)
// ---------------------------------------------------------------------------
__global__ void prep_kernel(const float* __restrict__ x, float* __restrict__ cur,
                            bf16* __restrict__ curb, uint8_t* __restrict__ curf8) {
  int i = (blockIdx.x * 256 + threadIdx.x) * 4;
  float4 v = *(const float4*)(x + i);
  *(float4*)(cur + i) = v;
  __hip_bfloat162 a, b;
  a.x = __float2bfloat16(v.x); a.y = __float2bfloat16(v.y);
  b.x = __float2bfloat16(v.z); b.y = __float2bfloat16(v.w);
  *(__hip_bfloat162*)(curb + i) = a;
  *(__hip_bfloat162*)(curb + i + 2) = b;
  uint32_t p = (uint32_t)to_fp8(v.x) | ((uint32_t)to_fp8(v.y) << 8) |
               ((uint32_t)to_fp8(v.z) << 16) | ((uint32_t)to_fp8(v.w) << 24);
  *(uint32_t*)(curf8 + i) = p;
}

// ---------------------------------------------------------------------------
// transpose + cast fp32 [R][C] -> bf16 [C][R]   (weights, tiny)
// ---------------------------------------------------------------------------
__global__ void transpose_cast(const float* __restrict__ in, bf16* __restrict__ out,
                               int R, int C) {
  __shared__ float tile[32][33];
  int c0 = blockIdx.x * 32, r0 = blockIdx.y * 32;
  int tx = threadIdx.x & 31, ty = threadIdx.x >> 5;  // 32 x 8
  for (int rr = ty; rr < 32; rr += 8)
    tile[rr][tx] = in[(size_t)(r0 + rr) * C + c0 + tx];
  __syncthreads();
  for (int cc = ty; cc < 32; cc += 8)
    out[(size_t)(c0 + cc) * R + r0 + tx] = __float2bfloat16(tile[tx][cc]);
}

// transpose + cast fp32 [R][C] -> fp8 [C][R]
__global__ void transpose_cast_fp8(const float* __restrict__ in,
                                   uint8_t* __restrict__ out, int R, int C) {
  __shared__ float tile[32][33];
  int c0 = blockIdx.x * 32, r0 = blockIdx.y * 32;
  int tx = threadIdx.x & 31, ty = threadIdx.x >> 5;
  for (int rr = ty; rr < 32; rr += 8)
    tile[rr][tx] = in[(size_t)(r0 + rr) * C + c0 + tx];
  __syncthreads();
  for (int cc = ty; cc < 32; cc += 8)
    out[(size_t)(c0 + cc) * R + r0 + tx] = to_fp8(tile[tx][cc]);
}

// ---------------------------------------------------------------------------
// QKV GEMM, MX-fp8: C[M,N] = A[M,K](fp8,rm) @ Bt[N,K](fp8,rm)^T + bias
// 128x128 tile, BK=128 (32KB LDS -> 3 blocks/CU), 16x16x128 scaled MFMA.
// (R3 lesson: double-buffering to 66KB LDS cut co-residency 3->2 blocks/CU
// and cost +14us/dispatch -- implicit 3-block overlap beats explicit dbuf.)
// n-tile = one (part,head) full d-range: part 0/1 (Q/K) fused expmap0 (+1/sqrt(d)
// for Q); part 2 (V) stored transposed to Vt[bh][d][s] bf16.
// C/D layout is shape-determined (== 16x16x32): col=lane&15, row=(lane>>4)*4+reg.
// ---------------------------------------------------------------------------
__global__ __launch_bounds__(256, 3)
void gemm_qkv_fp8(const uint8_t* __restrict__ A, const uint8_t* __restrict__ Bt,
                  const float* __restrict__ bias, bf16* __restrict__ Qo,
                  bf16* __restrict__ Ko, bf16* __restrict__ Vto, int M, int N,
                  int K) {
  __shared__ uint8_t As[128 * 128];
  __shared__ uint8_t Bs[128 * 128];
  __shared__ float red[2][128];
  const int t = threadIdx.x;
  const int w = t >> 6, lane = t & 63;
  const int lm = lane & 15, qd = lane >> 4;
  const int m0 = blockIdx.x * 128, n0 = blockIdx.y * 128;
  const int wm = (w & 1) * 64, wn = (w >> 1) * 64;

  const uint8_t* Ag = A + (size_t)m0 * K;
  const uint8_t* Bg = Bt + (size_t)n0 * K;

  f4v acc[4][4];
  f4v zero = {0.f, 0.f, 0.f, 0.f};
#pragma unroll
  for (int i = 0; i < 4; i++)
#pragma unroll
    for (int j = 0; j < 4; j++) acc[i][j] = zero;

  for (int k0 = 0; k0 < K; k0 += 128) {
#pragma unroll
    for (int c = 0; c < 4; c++) {
      int s = c * 256 + t;
      int r = s >> 3;
      int kc = (s & 7) ^ (r & 7);  // xor-swizzle 16B chunks within the 128B row
      gload16(Ag + (size_t)r * K + k0 + kc * 16, &As[s * 16]);
      gload16(Bg + (size_t)r * K + k0 + kc * 16, &Bs[s * 16]);
    }
    __syncthreads();
    i8v af[4], bfr[4];
#pragma unroll
    for (int tm = 0; tm < 4; tm++) {
      int row = wm + tm * 16 + lm;
      int ch = (qd * 2) ^ (row & 7);          // lane's 32B = chunks ch, ch^1
      union { int4 q[2]; i8v v; } u;
      u.q[0] = *(const int4*)&As[row * 128 + ch * 16];
      u.q[1] = *(const int4*)&As[row * 128 + (ch ^ 1) * 16];
      af[tm] = u.v;
    }
#pragma unroll
    for (int tn = 0; tn < 4; tn++) {
      int row = wn + tn * 16 + lm;
      int ch = (qd * 2) ^ (row & 7);
      union { int4 q[2]; i8v v; } u;
      u.q[0] = *(const int4*)&Bs[row * 128 + ch * 16];
      u.q[1] = *(const int4*)&Bs[row * 128 + (ch ^ 1) * 16];
      bfr[tn] = u.v;
    }
#pragma unroll
    for (int tm = 0; tm < 4; tm++)
#pragma unroll
      for (int tn = 0; tn < 4; tn++)
        acc[tm][tn] = mfma_fp8(af[tm], bfr[tn], acc[tm][tn]);
    __syncthreads();
  }

  const int part = n0 >> 10;  // block-uniform: 0=Q, 1=K, 2=V
  const int hh = (n0 >> 7) & 7;
  if (part == 2) {
#pragma unroll
    for (int tm = 0; tm < 4; tm++)
#pragma unroll
      for (int tn = 0; tn < 4; tn++) {
        int d = wn + tn * 16 + lm;
        float bv = bias[n0 + d];
        int row0 = m0 + wm + tm * 16 + qd * 4;
        int b = row0 >> 10, s0 = row0 & 1023;
        bf16 vt[4];
#pragma unroll
        for (int r = 0; r < 4; r++) vt[r] = __float2bfloat16(acc[tm][tn][r] + bv);
        *(ushort4*)&Vto[((size_t)(b * 8 + hh)) * 131072 + (size_t)d * 1024 + s0] =
            *(ushort4*)vt;
      }
  } else {
    float bvs[4];
#pragma unroll
    for (int tn = 0; tn < 4; tn++) bvs[tn] = bias[n0 + wn + tn * 16 + lm];
    float ss[4][4];
#pragma unroll
    for (int tm = 0; tm < 4; tm++)
#pragma unroll
      for (int r = 0; r < 4; r++) {
        float s = 0.f;
#pragma unroll
        for (int tn = 0; tn < 4; tn++) {
          float v = acc[tm][tn][r] + bvs[tn];
          s += v * v;
        }
#pragma unroll
        for (int off = 1; off < 16; off <<= 1) s += __shfl_xor(s, off, 64);
        ss[tm][r] = s;
      }
    if (lm == 0) {
#pragma unroll
      for (int tm = 0; tm < 4; tm++)
#pragma unroll
        for (int r = 0; r < 4; r++)
          red[w >> 1][wm + tm * 16 + qd * 4 + r] = ss[tm][r];
    }
    __syncthreads();
    const float qsc = (part == 0) ? 0.08838834764831845f : 1.0f;  // 1/sqrt(128)
    float scr[4][4];
#pragma unroll
    for (int tm = 0; tm < 4; tm++)
#pragma unroll
      for (int r = 0; r < 4; r++) {
        int row = wm + tm * 16 + qd * 4 + r;
        float tot = red[0][row] + red[1][row];
        float nrm = fmaxf(sqrtf(tot), 1e-7f);
        scr[tm][r] = tanhf(nrm) / nrm * qsc;
      }
    bf16* dst = (part == 0) ? Qo : Ko;
#pragma unroll
    for (int tm = 0; tm < 4; tm++)
#pragma unroll
      for (int tn = 0; tn < 4; tn++) {
        int d = wn + tn * 16 + lm;
        int row0 = m0 + wm + tm * 16 + qd * 4;
        int b = row0 >> 10, s0 = row0 & 1023;
#pragma unroll
        for (int r = 0; r < 4; r++)
          dst[(((size_t)(b * 8 + hh)) * 1024 + s0 + r) * 128 + d] =
              __float2bfloat16((acc[tm][tn][r] + bvs[tn]) * scr[tm][r]);
      }
  }
}

// ---------------------------------------------------------------------------
// GEMM (bf16): C[M,N] = A[M,K] @ Bt[N,K]^T + bias, fp32 out. (final projection)
// ---------------------------------------------------------------------------
__global__ __launch_bounds__(256, 3)
void gemm_bt(const bf16* __restrict__ A, const bf16* __restrict__ Bt,
             const float* __restrict__ bias, float* __restrict__ Cf, int M, int N,
             int K) {
  __shared__ bf16 As[128 * 64];
  __shared__ bf16 Bs[128 * 64];
  const int t = threadIdx.x;
  const int w = t >> 6, lane = t & 63;
  const int lm = lane & 15, qd = lane >> 4;
  const int m0 = blockIdx.x * 128, n0 = blockIdx.y * 128;
  const int wm = (w & 1) * 64, wn = (w >> 1) * 64;

  const bf16* Ag = A + (size_t)m0 * K;
  const bf16* Bg = Bt + (size_t)n0 * K;

  f4v acc[4][4];
  f4v zero = {0.f, 0.f, 0.f, 0.f};
#pragma unroll
  for (int i = 0; i < 4; i++)
#pragma unroll
    for (int j = 0; j < 4; j++) acc[i][j] = zero;

  for (int k0 = 0; k0 < K; k0 += 64) {
#pragma unroll
    for (int c = 0; c < 4; c++) {
      int s = c * 256 + t;
      int r = s >> 3;
      int kc = (s & 7) ^ (r & 7);
      gload16(Ag + (size_t)r * K + k0 + kc * 8, &As[s * 8]);
      gload16(Bg + (size_t)r * K + k0 + kc * 8, &Bs[s * 8]);
    }
    __syncthreads();
#pragma unroll
    for (int ks = 0; ks < 2; ks++) {
      b8 af[4], bfr[4];
#pragma unroll
      for (int tm = 0; tm < 4; tm++) {
        int row = wm + tm * 16 + lm;
        int ch = (ks * 4 + qd) ^ (row & 7);
        af[tm] = *(const b8*)&As[row * 64 + ch * 8];
      }
#pragma unroll
      for (int tn = 0; tn < 4; tn++) {
        int row = wn + tn * 16 + lm;
        int ch = (ks * 4 + qd) ^ (row & 7);
        bfr[tn] = *(const b8*)&Bs[row * 64 + ch * 8];
      }
#pragma unroll
      for (int tm = 0; tm < 4; tm++)
#pragma unroll
        for (int tn = 0; tn < 4; tn++)
          acc[tm][tn] = mfma_bf16(af[tm], bfr[tn], acc[tm][tn]);
    }
    __syncthreads();
  }

#pragma unroll
  for (int tm = 0; tm < 4; tm++)
#pragma unroll
    for (int tn = 0; tn < 4; tn++) {
      int col = n0 + wn + tn * 16 + lm;
      float bv = bias[col];
#pragma unroll
      for (int r = 0; r < 4; r++) {
        int row = m0 + wm + tm * 16 + qd * 4 + r;
        Cf[(size_t)row * N + col] = acc[tm][tn][r] + bv;
      }
    }
}

// ---------------------------------------------------------------------------
// Flash attention v3, no-max softmax (|score| <= 1/sqrt(128)).
// l via MFMA against all-ones B. grid (64 bh, 8 qt) => same-bh same-XCD.
// 4 waves x 32 q-rows; K fragments shared across both m-tiles.
// R6 analysis: FETCH was 25MB vs 48MB of Q/K/V -- KV is fully L2/L3-resident
// (same-bh blocks pinned to one XCD), so LDS staging was protecting a cache
// that needs no protection, while costing 2 barriers x 16 tiles of lockstep,
// staging DMA, K/V LDS bank conflicts, and an 80KB footprint (2 blocks/CU).
// v3 reads K and V MFMA fragments DIRECTLY from global (L2): per-wave b8
// loads coalesce as 64B-contiguous spans per 256B row. P stays in per-wave
// LDS (16KB/block, no cross-wave sharing) => ZERO barriers; waves free-run
// and the compiler pipelines loads across tiles. (Guide common-mistake #7 /
// m169: same-S precedent, dropping V-staging at S=1024 was +26%.)
// ---------------------------------------------------------------------------
__global__ __launch_bounds__(256, 2)
void attn_kernel(const bf16* __restrict__ Qf, const bf16* __restrict__ Kf,
                 const bf16* __restrict__ Vt, bf16* __restrict__ O) {
  __shared__ bf16 smem[8192];             // 16KB: P only, [4 waves][32 q][64 s']
  const int t = threadIdx.x, w = t >> 6, lane = t & 63;
  const int lm = lane & 15, qd = lane >> 4;
  const int bh = blockIdx.x, qt = blockIdx.y;
  const bf16* Qg = Qf + ((size_t)bh * 1024 + qt * 128) * 128;
  const bf16* Kg = Kf + (size_t)bh * 131072;
  const bf16* Vg = Vt + (size_t)bh * 131072;
  bf16* Pw = smem + w * 2048;

  b8 qfr[2][4];
#pragma unroll
  for (int mt = 0; mt < 2; mt++)
#pragma unroll
    for (int ks = 0; ks < 4; ks++)
      qfr[mt][ks] =
          *(const b8*)(Qg + (size_t)(w * 32 + mt * 16 + lm) * 128 + ks * 32 + qd * 8);

  f4v o[2][8];
  f4v lacc[2];
  f4v zero = {0.f, 0.f, 0.f, 0.f};
#pragma unroll
  for (int mt = 0; mt < 2; mt++) {
    lacc[mt] = zero;
#pragma unroll
    for (int i = 0; i < 8; i++) o[mt][i] = zero;
  }
  union { s8v s; b8 b; } uo;
#pragma unroll
  for (int i = 0; i < 8; i++) uo.s[i] = 0x3F80;  // bf16 1.0
  const b8 ones = uo.b;

  for (int kt = 0; kt < 16; kt++) {
    // scores: K fragments straight from global (L2-hit); read once per tn/ks,
    // used by both m-tiles
    f4v sc[2][4];
#pragma unroll
    for (int mt = 0; mt < 2; mt++)
#pragma unroll
      for (int tn = 0; tn < 4; tn++) sc[mt][tn] = zero;
#pragma unroll
    for (int tn = 0; tn < 4; tn++) {
      const bf16* kr = Kg + (size_t)(kt * 64 + tn * 16 + lm) * 128 + qd * 8;
#pragma unroll
      for (int ks = 0; ks < 4; ks++) {
        b8 kfr = *(const b8*)(kr + ks * 32);
        sc[0][tn] = mfma_bf16(qfr[0][ks], kfr, sc[0][tn]);
        sc[1][tn] = mfma_bf16(qfr[1][ks], kfr, sc[1][tn]);
      }
    }
    // P = exp(s) -> per-wave LDS (perm swizzle (q>>1)&7); no barrier needed
#pragma unroll
    for (int mt = 0; mt < 2; mt++)
#pragma unroll
      for (int tn = 0; tn < 4; tn++)
#pragma unroll
        for (int r = 0; r < 4; r++) {
          int qi = mt * 16 + qd * 4 + r;
          int ch = (tn * 2 + (lm >> 3)) ^ ((qi >> 1) & 7);
          Pw[qi * 64 + ch * 8 + (lm & 7)] = __float2bfloat16(__expf(sc[mt][tn][r]));
        }

    b8 pa[2][2];
#pragma unroll
    for (int mt = 0; mt < 2; mt++)
#pragma unroll
      for (int kv2 = 0; kv2 < 2; kv2++) {
        int qi = mt * 16 + lm;
        int ch = (kv2 * 4 + qd) ^ ((lm >> 1) & 7);
        pa[mt][kv2] = *(const b8*)&Pw[qi * 64 + ch * 8];
      }
#pragma unroll
    for (int mt = 0; mt < 2; mt++)
#pragma unroll
      for (int kv2 = 0; kv2 < 2; kv2++)
        lacc[mt] = mfma_bf16(pa[mt][kv2], ones, lacc[mt]);
    // PV: V fragments straight from global (Vt[bh][d][s] rows are over s=k)
#pragma unroll
    for (int tnd = 0; tnd < 8; tnd++) {
      const bf16* vr = Vg + (size_t)(tnd * 16 + lm) * 1024 + kt * 64 + qd * 8;
#pragma unroll
      for (int kv2 = 0; kv2 < 2; kv2++) {
        b8 vfr = *(const b8*)(vr + kv2 * 32);
#pragma unroll
        for (int mt = 0; mt < 2; mt++)
          o[mt][tnd] = mfma_bf16(pa[mt][kv2], vfr, o[mt][tnd]);
      }
    }
  }

  const int b = bh >> 3, h = bh & 7;
#pragma unroll
  for (int mt = 0; mt < 2; mt++) {
    float rinv[4];
#pragma unroll
    for (int r = 0; r < 4; r++) rinv[r] = 1.0f / lacc[mt][r];
#pragma unroll
    for (int tnd = 0; tnd < 8; tnd++) {
      int d = tnd * 16 + lm;
#pragma unroll
      for (int r = 0; r < 4; r++) {
        int sIdx = qt * 128 + w * 32 + mt * 16 + qd * 4 + r;
        O[((size_t)b * 1024 + sIdx) * 1024 + h * 128 + d] =
            __float2bfloat16(o[mt][tnd][r] * rinv[r]);
      }
    }
  }
}

// ---------------------------------------------------------------------------
// update v4: m = o @ W_pinv + b_pinv (rank-8), upd = m @ W_attn[l] + b_attn[l],
// cur += upd, curb = bf16(cur), curf8 = fp8(cur).
// Streamed to fit 64 VGPR with no scratch spills (R5 lesson: spills cost 80MB
// of HBM write-back). Coalesced chunks of 4: h(c) = c*256 + lane*4 (R4 lesson:
// contiguous-16-per-lane caused 4x write amplification).
// ---------------------------------------------------------------------------
__global__ __launch_bounds__(256, 4)
void update_kernel(const bf16* __restrict__ O, const float* __restrict__ Wpinv,
                   const float* __restrict__ bpinv, const float* __restrict__ Wattn,
                   const float* __restrict__ battn, float* __restrict__ cur,
                   bf16* __restrict__ curb, uint8_t* __restrict__ curf8) {
  const int t = threadIdx.x, w = t >> 6, lane = t & 63;
  const int r0 = blockIdx.x * 8 + w * 2;  // this wave: rows r0, r0+1
  const int hb = lane * 4;                // base within each 256-column chunk

  // ---- phase A (streamed): a = O-row . Wpinv partials over this lane's h ----
  float a0[8], a1[8];
#pragma unroll
  for (int j = 0; j < 8; j++) { a0[j] = 0.f; a1[j] = 0.f; }
#pragma unroll
  for (int c = 0; c < 4; c++) {
    const bf16* p0 = O + (size_t)r0 * 1024 + c * 256 + hb;
    bf16 t0[4], t1[4];
    *(ushort4*)t0 = *(const ushort4*)p0;
    *(ushort4*)t1 = *(const ushort4*)(p0 + 1024);
#pragma unroll
    for (int e = 0; e < 4; e++) {
      float v0 = __bfloat162float(t0[e]);
      float v1 = __bfloat162float(t1[e]);
      const float* wr = Wpinv + (size_t)(c * 256 + hb + e) * 8;
      float4 wa = *(const float4*)wr;
      float4 wb = *(const float4*)(wr + 4);
      a0[0] += v0 * wa.x; a0[1] += v0 * wa.y;
      a0[2] += v0 * wa.z; a0[3] += v0 * wa.w;
      a0[4] += v0 * wb.x; a0[5] += v0 * wb.y;
      a0[6] += v0 * wb.z; a0[7] += v0 * wb.w;
      a1[0] += v1 * wa.x; a1[1] += v1 * wa.y;
      a1[2] += v1 * wa.z; a1[3] += v1 * wa.w;
      a1[4] += v1 * wb.x; a1[5] += v1 * wb.y;
      a1[6] += v1 * wb.z; a1[7] += v1 * wb.w;
    }
  }
  // butterfly over the wave: every lane ends with the full sum
#pragma unroll
  for (int j = 0; j < 8; j++) {
#pragma unroll
    for (int off = 32; off; off >>= 1) {
      a0[j] += __shfl_xor(a0[j], off, 64);
      a1[j] += __shfl_xor(a1[j], off, 64);
    }
  }
#pragma unroll
  for (int j = 0; j < 8; j++) {
    float bp = bpinv[j];
    a0[j] += bp;   // a0/a1 now hold m0/m1
    a1[j] += bp;
  }

  // ---- phase B (streamed): per chunk, compute upd and retire immediately ----
#pragma unroll
  for (int c = 0; c < 4; c++) {
    float4 bv = *(const float4*)(battn + c * 256 + hb);
    float u00 = bv.x, u01 = bv.y, u02 = bv.z, u03 = bv.w;
    float u10 = bv.x, u11 = bv.y, u12 = bv.z, u13 = bv.w;
#pragma unroll
    for (int j = 0; j < 8; j++) {
      float4 wv = *(const float4*)(Wattn + (size_t)j * 1024 + c * 256 + hb);
      u00 += a0[j] * wv.x; u01 += a0[j] * wv.y;
      u02 += a0[j] * wv.z; u03 += a0[j] * wv.w;
      u10 += a1[j] * wv.x; u11 += a1[j] * wv.y;
      u12 += a1[j] * wv.z; u13 += a1[j] * wv.w;
    }
    // row r0
    {
      float* cp = cur + (size_t)r0 * 1024 + c * 256 + hb;
      float4 c4 = *(float4*)cp;
      c4.x += u00; c4.y += u01; c4.z += u02; c4.w += u03;
      *(float4*)cp = c4;
      bf16 cb[4];
      cb[0] = __float2bfloat16(c4.x); cb[1] = __float2bfloat16(c4.y);
      cb[2] = __float2bfloat16(c4.z); cb[3] = __float2bfloat16(c4.w);
      *(ushort4*)(curb + (size_t)r0 * 1024 + c * 256 + hb) = *(ushort4*)cb;
      uint32_t p = (uint32_t)to_fp8(c4.x) | ((uint32_t)to_fp8(c4.y) << 8) |
                   ((uint32_t)to_fp8(c4.z) << 16) | ((uint32_t)to_fp8(c4.w) << 24);
      *(uint32_t*)(curf8 + (size_t)r0 * 1024 + c * 256 + hb) = p;
    }
    // row r0+1
    {
      float* cp = cur + (size_t)(r0 + 1) * 1024 + c * 256 + hb;
      float4 c4 = *(float4*)cp;
      c4.x += u10; c4.y += u11; c4.z += u12; c4.w += u13;
      *(float4*)cp = c4;
      bf16 cb[4];
      cb[0] = __float2bfloat16(c4.x); cb[1] = __float2bfloat16(c4.y);
      cb[2] = __float2bfloat16(c4.z); cb[3] = __float2bfloat16(c4.w);
      *(ushort4*)(curb + (size_t)(r0 + 1) * 1024 + c * 256 + hb) = *(ushort4*)cb;
      uint32_t p = (uint32_t)to_fp8(c4.x) | ((uint32_t)to_fp8(c4.y) << 8) |
                   ((uint32_t)to_fp8(c4.z) << 16) | ((uint32_t)to_fp8(c4.w) << 24);
      *(uint32_t*)(curf8 + (size_t)(r0 + 1) * 1024 + c * 256 + hb) = p;
    }
  }
}

// ---------------------------------------------------------------------------
extern "C" void kernel_launch(void* const* d_in, const int* in_sizes, int n_in,
                              void* d_out, int out_size, void* d_ws, size_t ws_size,
                              hipStream_t stream) {
  const float* x      = (const float*)d_in[0];
  const float* W_qkv  = (const float*)d_in[1];
  const float* b_qkv  = (const float*)d_in[2];
  const float* W_pinv = (const float*)d_in[3];
  const float* b_pinv = (const float*)d_in[4];
  const float* W_attn = (const float*)d_in[5];
  const float* b_attn = (const float*)d_in[6];
  const float* W_out  = (const float*)d_in[7];
  const float* b_out  = (const float*)d_in[8];

  char* ws = (char*)d_ws;
  size_t off = 0;
  auto alloc = [&](size_t bytes) -> void* {
    void* p = ws + off;
    off += (bytes + 255) & ~(size_t)255;
    return p;
  };
  float* cur     = (float*)alloc((size_t)8192 * 1024 * 4);    // 32MB
  bf16* curb     = (bf16*)alloc((size_t)8192 * 1024 * 2);     // 16MB
  uint8_t* curf8 = (uint8_t*)alloc((size_t)8192 * 1024);      // 8MB
  uint8_t* Wqkv8 = (uint8_t*)alloc((size_t)3072 * 1024);      // 3MB [3072][1024] fp8
  bf16* Woutt    = (bf16*)alloc((size_t)1024 * 1024 * 2);     // 2MB
  bf16* Q        = (bf16*)alloc((size_t)8192 * 1024 * 2);     // 16MB [B,H,S,HD] flowed
  bf16* Kt       = (bf16*)alloc((size_t)8192 * 1024 * 2);     // 16MB [B,H,S,HD] flowed
  bf16* Vt       = (bf16*)alloc((size_t)8192 * 1024 * 2);     // 16MB [B,H,HD,S]
  bf16* O        = (bf16*)alloc((size_t)8192 * 1024 * 2);     // 16MB
  (void)ws_size; (void)in_sizes; (void)n_in; (void)out_size;

  prep_kernel<<<8192, 256, 0, stream>>>(x, cur, curb, curf8);
  transpose_cast_fp8<<<dim3(96, 32), 256, 0, stream>>>(W_qkv, Wqkv8, 1024, 3072);
  transpose_cast<<<dim3(32, 32), 256, 0, stream>>>(W_out, Woutt, 1024, 1024);

  for (int l = 0; l < 3; l++) {
    gemm_qkv_fp8<<<dim3(64, 24), 256, 0, stream>>>(curf8, Wqkv8, b_qkv, Q, Kt, Vt,
                                                   8192, 3072, 1024);
    attn_kernel<<<dim3(64, 8), 256, 0, stream>>>(Q, Kt, Vt, O);
    update_kernel<<<1024, 256, 0, stream>>>(O, W_pinv, b_pinv,
                                            W_attn + (size_t)l * 8 * 1024,
                                            b_attn + (size_t)l * 1024, cur, curb,
                                            curf8);
  }
  gemm_bt<<<dim3(64, 8), 256, 0, stream>>>(curb, Woutt, b_out, (float*)d_out, 8192,
                                           1024, 1024);
}

// Round 8
// 503.156 us; speedup vs baseline: 1.4543x; 1.4543x over previous
//
#include <hip/hip_runtime.h>
#include <hip/hip_bf16.h>
#include <hip/hip_fp8.h>
#include <cstdint>

typedef __hip_bfloat16 bf16;
typedef __bf16 b8 __attribute__((ext_vector_type(8)));
typedef float f4v __attribute__((ext_vector_type(4)));
typedef short s8v __attribute__((ext_vector_type(8)));
typedef int i8v __attribute__((ext_vector_type(8)));

#define DEVI static __device__ __forceinline__

// async global->LDS, 16B per lane. LDS dest is wave-uniform base + lane*16.
DEVI void gload16(const void* g, void* l) {
  __builtin_amdgcn_global_load_lds(
      (const __attribute__((address_space(1))) void*)(uintptr_t)g,
      (__attribute__((address_space(3))) void*)(uint32_t)(uintptr_t)l,
      16, 0, 0);
}

DEVI f4v mfma_bf16(b8 a, b8 b, f4v c) {
  return __builtin_amdgcn_mfma_f32_16x16x32_bf16(a, b, c, 0, 0, 0);
}

// MX-scaled fp8 (OCP e4m3), K=128, unit scales (E8M0 127 = 2^0 in every byte).
DEVI f4v mfma_fp8(i8v a, i8v b, f4v c) {
  return __builtin_amdgcn_mfma_scale_f32_16x16x128_f8f6f4(
      a, b, c, 0, 0, 0, 0x7F7F7F7F, 0, 0x7F7F7F7F);
}

DEVI uint8_t to_fp8(float f) {
  __hip_fp8_e4m3 v(f);
  return v.__x;
}

// ---------------------------------------------------------------------------
// prep: x -> cur (fp32) + curb (bf16) + curf8 (fp8 e4m3)
// ---------------------------------------------------------------------------
__global__ void prep_kernel(const float* __restrict__ x, float* __restrict__ cur,
                            bf16* __restrict__ curb, uint8_t* __restrict__ curf8) {
  int i = (blockIdx.x * 256 + threadIdx.x) * 4;
  float4 v = *(const float4*)(x + i);
  *(float4*)(cur + i) = v;
  __hip_bfloat162 a, b;
  a.x = __float2bfloat16(v.x); a.y = __float2bfloat16(v.y);
  b.x = __float2bfloat16(v.z); b.y = __float2bfloat16(v.w);
  *(__hip_bfloat162*)(curb + i) = a;
  *(__hip_bfloat162*)(curb + i + 2) = b;
  uint32_t p = (uint32_t)to_fp8(v.x) | ((uint32_t)to_fp8(v.y) << 8) |
               ((uint32_t)to_fp8(v.z) << 16) | ((uint32_t)to_fp8(v.w) << 24);
  *(uint32_t*)(curf8 + i) = p;
}

// ---------------------------------------------------------------------------
// transpose + cast fp32 [R][C] -> bf16 [C][R]   (weights, tiny)
// ---------------------------------------------------------------------------
__global__ void transpose_cast(const float* __restrict__ in, bf16* __restrict__ out,
                               int R, int C) {
  __shared__ float tile[32][33];
  int c0 = blockIdx.x * 32, r0 = blockIdx.y * 32;
  int tx = threadIdx.x & 31, ty = threadIdx.x >> 5;  // 32 x 8
  for (int rr = ty; rr < 32; rr += 8)
    tile[rr][tx] = in[(size_t)(r0 + rr) * C + c0 + tx];
  __syncthreads();
  for (int cc = ty; cc < 32; cc += 8)
    out[(size_t)(c0 + cc) * R + r0 + tx] = __float2bfloat16(tile[tx][cc]);
}

// transpose + cast fp32 [R][C] -> fp8 [C][R]
__global__ void transpose_cast_fp8(const float* __restrict__ in,
                                   uint8_t* __restrict__ out, int R, int C) {
  __shared__ float tile[32][33];
  int c0 = blockIdx.x * 32, r0 = blockIdx.y * 32;
  int tx = threadIdx.x & 31, ty = threadIdx.x >> 5;
  for (int rr = ty; rr < 32; rr += 8)
    tile[rr][tx] = in[(size_t)(r0 + rr) * C + c0 + tx];
  __syncthreads();
  for (int cc = ty; cc < 32; cc += 8)
    out[(size_t)(c0 + cc) * R + r0 + tx] = to_fp8(tile[tx][cc]);
}

// ---------------------------------------------------------------------------
// QKV GEMM, MX-fp8: C[M,N] = A[M,K](fp8,rm) @ Bt[N,K](fp8,rm)^T + bias
// 128x128 tile, BK=128 (32KB LDS -> 3 blocks/CU), 16x16x128 scaled MFMA.
// (R3 lesson: double-buffering to 66KB LDS cut co-residency 3->2 blocks/CU
// and cost +14us/dispatch -- implicit 3-block overlap beats explicit dbuf.)
// n-tile = one (part,head) full d-range: part 0/1 (Q/K) fused expmap0 (+1/sqrt(d)
// for Q); part 2 (V) stored transposed to Vt[bh][d][s] bf16.
// C/D layout is shape-determined (== 16x16x32): col=lane&15, row=(lane>>4)*4+reg.
// ---------------------------------------------------------------------------
__global__ __launch_bounds__(256, 3)
void gemm_qkv_fp8(const uint8_t* __restrict__ A, const uint8_t* __restrict__ Bt,
                  const float* __restrict__ bias, bf16* __restrict__ Qo,
                  bf16* __restrict__ Ko, bf16* __restrict__ Vto, int M, int N,
                  int K) {
  __shared__ uint8_t As[128 * 128];
  __shared__ uint8_t Bs[128 * 128];
  __shared__ float red[2][128];
  const int t = threadIdx.x;
  const int w = t >> 6, lane = t & 63;
  const int lm = lane & 15, qd = lane >> 4;
  const int m0 = blockIdx.x * 128, n0 = blockIdx.y * 128;
  const int wm = (w & 1) * 64, wn = (w >> 1) * 64;

  const uint8_t* Ag = A + (size_t)m0 * K;
  const uint8_t* Bg = Bt + (size_t)n0 * K;

  f4v acc[4][4];
  f4v zero = {0.f, 0.f, 0.f, 0.f};
#pragma unroll
  for (int i = 0; i < 4; i++)
#pragma unroll
    for (int j = 0; j < 4; j++) acc[i][j] = zero;

  for (int k0 = 0; k0 < K; k0 += 128) {
#pragma unroll
    for (int c = 0; c < 4; c++) {
      int s = c * 256 + t;
      int r = s >> 3;
      int kc = (s & 7) ^ (r & 7);  // xor-swizzle 16B chunks within the 128B row
      gload16(Ag + (size_t)r * K + k0 + kc * 16, &As[s * 16]);
      gload16(Bg + (size_t)r * K + k0 + kc * 16, &Bs[s * 16]);
    }
    __syncthreads();
    i8v af[4], bfr[4];
#pragma unroll
    for (int tm = 0; tm < 4; tm++) {
      int row = wm + tm * 16 + lm;
      int ch = (qd * 2) ^ (row & 7);          // lane's 32B = chunks ch, ch^1
      union { int4 q[2]; i8v v; } u;
      u.q[0] = *(const int4*)&As[row * 128 + ch * 16];
      u.q[1] = *(const int4*)&As[row * 128 + (ch ^ 1) * 16];
      af[tm] = u.v;
    }
#pragma unroll
    for (int tn = 0; tn < 4; tn++) {
      int row = wn + tn * 16 + lm;
      int ch = (qd * 2) ^ (row & 7);
      union { int4 q[2]; i8v v; } u;
      u.q[0] = *(const int4*)&Bs[row * 128 + ch * 16];
      u.q[1] = *(const int4*)&Bs[row * 128 + (ch ^ 1) * 16];
      bfr[tn] = u.v;
    }
#pragma unroll
    for (int tm = 0; tm < 4; tm++)
#pragma unroll
      for (int tn = 0; tn < 4; tn++)
        acc[tm][tn] = mfma_fp8(af[tm], bfr[tn], acc[tm][tn]);
    __syncthreads();
  }

  const int part = n0 >> 10;  // block-uniform: 0=Q, 1=K, 2=V
  const int hh = (n0 >> 7) & 7;
  if (part == 2) {
#pragma unroll
    for (int tm = 0; tm < 4; tm++)
#pragma unroll
      for (int tn = 0; tn < 4; tn++) {
        int d = wn + tn * 16 + lm;
        float bv = bias[n0 + d];
        int row0 = m0 + wm + tm * 16 + qd * 4;
        int b = row0 >> 10, s0 = row0 & 1023;
        bf16 vt[4];
#pragma unroll
        for (int r = 0; r < 4; r++) vt[r] = __float2bfloat16(acc[tm][tn][r] + bv);
        *(ushort4*)&Vto[((size_t)(b * 8 + hh)) * 131072 + (size_t)d * 1024 + s0] =
            *(ushort4*)vt;
      }
  } else {
    float bvs[4];
#pragma unroll
    for (int tn = 0; tn < 4; tn++) bvs[tn] = bias[n0 + wn + tn * 16 + lm];
    float ss[4][4];
#pragma unroll
    for (int tm = 0; tm < 4; tm++)
#pragma unroll
      for (int r = 0; r < 4; r++) {
        float s = 0.f;
#pragma unroll
        for (int tn = 0; tn < 4; tn++) {
          float v = acc[tm][tn][r] + bvs[tn];
          s += v * v;
        }
#pragma unroll
        for (int off = 1; off < 16; off <<= 1) s += __shfl_xor(s, off, 64);
        ss[tm][r] = s;
      }
    if (lm == 0) {
#pragma unroll
      for (int tm = 0; tm < 4; tm++)
#pragma unroll
        for (int r = 0; r < 4; r++)
          red[w >> 1][wm + tm * 16 + qd * 4 + r] = ss[tm][r];
    }
    __syncthreads();
    const float qsc = (part == 0) ? 0.08838834764831845f : 1.0f;  // 1/sqrt(128)
    float scr[4][4];
#pragma unroll
    for (int tm = 0; tm < 4; tm++)
#pragma unroll
      for (int r = 0; r < 4; r++) {
        int row = wm + tm * 16 + qd * 4 + r;
        float tot = red[0][row] + red[1][row];
        float nrm = fmaxf(sqrtf(tot), 1e-7f);
        scr[tm][r] = tanhf(nrm) / nrm * qsc;
      }
    bf16* dst = (part == 0) ? Qo : Ko;
#pragma unroll
    for (int tm = 0; tm < 4; tm++)
#pragma unroll
      for (int tn = 0; tn < 4; tn++) {
        int d = wn + tn * 16 + lm;
        int row0 = m0 + wm + tm * 16 + qd * 4;
        int b = row0 >> 10, s0 = row0 & 1023;
#pragma unroll
        for (int r = 0; r < 4; r++)
          dst[(((size_t)(b * 8 + hh)) * 1024 + s0 + r) * 128 + d] =
              __float2bfloat16((acc[tm][tn][r] + bvs[tn]) * scr[tm][r]);
      }
  }
}

// ---------------------------------------------------------------------------
// GEMM (bf16): C[M,N] = A[M,K] @ Bt[N,K]^T + bias, fp32 out. (final projection)
// ---------------------------------------------------------------------------
__global__ __launch_bounds__(256, 3)
void gemm_bt(const bf16* __restrict__ A, const bf16* __restrict__ Bt,
             const float* __restrict__ bias, float* __restrict__ Cf, int M, int N,
             int K) {
  __shared__ bf16 As[128 * 64];
  __shared__ bf16 Bs[128 * 64];
  const int t = threadIdx.x;
  const int w = t >> 6, lane = t & 63;
  const int lm = lane & 15, qd = lane >> 4;
  const int m0 = blockIdx.x * 128, n0 = blockIdx.y * 128;
  const int wm = (w & 1) * 64, wn = (w >> 1) * 64;

  const bf16* Ag = A + (size_t)m0 * K;
  const bf16* Bg = Bt + (size_t)n0 * K;

  f4v acc[4][4];
  f4v zero = {0.f, 0.f, 0.f, 0.f};
#pragma unroll
  for (int i = 0; i < 4; i++)
#pragma unroll
    for (int j = 0; j < 4; j++) acc[i][j] = zero;

  for (int k0 = 0; k0 < K; k0 += 64) {
#pragma unroll
    for (int c = 0; c < 4; c++) {
      int s = c * 256 + t;
      int r = s >> 3;
      int kc = (s & 7) ^ (r & 7);
      gload16(Ag + (size_t)r * K + k0 + kc * 8, &As[s * 8]);
      gload16(Bg + (size_t)r * K + k0 + kc * 8, &Bs[s * 8]);
    }
    __syncthreads();
#pragma unroll
    for (int ks = 0; ks < 2; ks++) {
      b8 af[4], bfr[4];
#pragma unroll
      for (int tm = 0; tm < 4; tm++) {
        int row = wm + tm * 16 + lm;
        int ch = (ks * 4 + qd) ^ (row & 7);
        af[tm] = *(const b8*)&As[row * 64 + ch * 8];
      }
#pragma unroll
      for (int tn = 0; tn < 4; tn++) {
        int row = wn + tn * 16 + lm;
        int ch = (ks * 4 + qd) ^ (row & 7);
        bfr[tn] = *(const b8*)&Bs[row * 64 + ch * 8];
      }
#pragma unroll
      for (int tm = 0; tm < 4; tm++)
#pragma unroll
        for (int tn = 0; tn < 4; tn++)
          acc[tm][tn] = mfma_bf16(af[tm], bfr[tn], acc[tm][tn]);
    }
    __syncthreads();
  }

#pragma unroll
  for (int tm = 0; tm < 4; tm++)
#pragma unroll
    for (int tn = 0; tn < 4; tn++) {
      int col = n0 + wn + tn * 16 + lm;
      float bv = bias[col];
#pragma unroll
      for (int r = 0; r < 4; r++) {
        int row = m0 + wm + tm * 16 + qd * 4 + r;
        Cf[(size_t)row * N + col] = acc[tm][tn][r] + bv;
      }
    }
}

// ---------------------------------------------------------------------------
// Flash attention (R6 form, best known), no-max softmax.
// R7 lesson: removing K/V LDS staging starved MFMA on ~200cy L2 latency per
// fragment (MfmaUtil 27->11, dur 51->128us) -- staging is latency
// amortization, not bandwidth protection; FETCH_SIZE can't see that.
// 4 waves x 32 q-rows; K-fragments read once, shared across both m-tiles.
// K/V double-buffered (2x16KB each + 16KB P = 80KB): prefetch tile kt+1
// during compute of kt; counted s_waitcnt vmcnt(8) + raw s_barrier.
// NEW (T5): s_setprio(1) around the two MFMA clusters -- the 2 co-resident
// blocks/CU run at independent phases, so the CU scheduler can favor the
// MFMA-issuing wave over the other block's staging (m191: +4-7% attn).
// ---------------------------------------------------------------------------
__global__ __launch_bounds__(256, 2)
void attn_kernel(const bf16* __restrict__ Qf, const bf16* __restrict__ Kf,
                 const bf16* __restrict__ Vt, bf16* __restrict__ O) {
  __shared__ bf16 smem[40960];            // 81920 B = 2x(K 8192 + V 8192) + P 8192
  bf16* Ps = smem + 32768;                // [4 waves][32 q][64 s'] perm-swizzled
  const int t = threadIdx.x, w = t >> 6, lane = t & 63;
  const int lm = lane & 15, qd = lane >> 4;
  const int bh = blockIdx.x, qt = blockIdx.y;
  const bf16* Qg = Qf + ((size_t)bh * 1024 + qt * 128) * 128;
  const bf16* Kg = Kf + (size_t)bh * 131072;
  const bf16* Vg = Vt + (size_t)bh * 131072;
  bf16* Pw = Ps + w * 2048;

  // stage K/V tile kt into buffer b (8 gload_lds per thread)
  auto stage = [&](int kt, int b) {
    bf16* Ksb = smem + b * 16384;
    bf16* Vsb = Ksb + 8192;
#pragma unroll
    for (int c = 0; c < 4; c++) {
      int s = c * 256 + t;
      int r = s >> 4;
      int kc = (s & 15) ^ (r & 7);
      gload16(Kg + (size_t)(kt * 64 + r) * 128 + kc * 8, &Ksb[s * 8]);
      int rv = s >> 3;
      int kv = (s & 7) ^ (rv & 7);
      gload16(Vg + (size_t)rv * 1024 + kt * 64 + kv * 8, &Vsb[s * 8]);
    }
  };

  b8 qfr[2][4];
#pragma unroll
  for (int mt = 0; mt < 2; mt++)
#pragma unroll
    for (int ks = 0; ks < 4; ks++)
      qfr[mt][ks] =
          *(const b8*)(Qg + (size_t)(w * 32 + mt * 16 + lm) * 128 + ks * 32 + qd * 8);

  f4v o[2][8];
  f4v lacc[2];
  f4v zero = {0.f, 0.f, 0.f, 0.f};
#pragma unroll
  for (int mt = 0; mt < 2; mt++) {
    lacc[mt] = zero;
#pragma unroll
    for (int i = 0; i < 8; i++) o[mt][i] = zero;
  }
  union { s8v s; b8 b; } uo;
#pragma unroll
  for (int i = 0; i < 8; i++) uo.s[i] = 0x3F80;  // bf16 1.0
  const b8 ones = uo.b;

  stage(0, 0);
  for (int kt = 0; kt < 16; kt++) {
    const int cb = kt & 1;
    if (kt < 15) {
      stage(kt + 1, cb ^ 1);                         // prefetch next tile
      asm volatile("s_waitcnt vmcnt(8)" ::: "memory");  // wait current tile only
    } else {
      asm volatile("s_waitcnt vmcnt(0)" ::: "memory");
    }
    __builtin_amdgcn_sched_barrier(0);
    __builtin_amdgcn_s_barrier();       // all threads' current-tile DMA landed
    __builtin_amdgcn_sched_barrier(0);  // pin ds_reads below the barrier
    const bf16* Ks = smem + cb * 16384;
    const bf16* Vs = Ks + 8192;

    // scores: K frags read ONCE, used by both m-tiles
    f4v sc[2][4];
#pragma unroll
    for (int mt = 0; mt < 2; mt++)
#pragma unroll
      for (int tn = 0; tn < 4; tn++) sc[mt][tn] = zero;
    __builtin_amdgcn_s_setprio(1);
#pragma unroll
    for (int tn = 0; tn < 4; tn++) {
      int krow = tn * 16 + lm;
#pragma unroll
      for (int ks = 0; ks < 4; ks++) {
        int ch = (ks * 4 + qd) ^ (krow & 7);
        b8 kfr = *(const b8*)&Ks[krow * 128 + ch * 8];
        sc[0][tn] = mfma_bf16(qfr[0][ks], kfr, sc[0][tn]);
        sc[1][tn] = mfma_bf16(qfr[1][ks], kfr, sc[1][tn]);
      }
    }
    __builtin_amdgcn_s_setprio(0);
    // P = exp(s) -> LDS (perm swizzle (q>>1)&7)
#pragma unroll
    for (int mt = 0; mt < 2; mt++)
#pragma unroll
      for (int tn = 0; tn < 4; tn++)
#pragma unroll
        for (int r = 0; r < 4; r++) {
          int qi = mt * 16 + qd * 4 + r;
          int ch = (tn * 2 + (lm >> 3)) ^ ((qi >> 1) & 7);
          Pw[qi * 64 + ch * 8 + (lm & 7)] = __float2bfloat16(__expf(sc[mt][tn][r]));
        }

    b8 pa[2][2];
#pragma unroll
    for (int mt = 0; mt < 2; mt++)
#pragma unroll
      for (int kv2 = 0; kv2 < 2; kv2++) {
        int qi = mt * 16 + lm;
        int ch = (kv2 * 4 + qd) ^ ((lm >> 1) & 7);
        pa[mt][kv2] = *(const b8*)&Pw[qi * 64 + ch * 8];
      }
    __builtin_amdgcn_s_setprio(1);
#pragma unroll
    for (int mt = 0; mt < 2; mt++)
#pragma unroll
      for (int kv2 = 0; kv2 < 2; kv2++)
        lacc[mt] = mfma_bf16(pa[mt][kv2], ones, lacc[mt]);
#pragma unroll
    for (int tnd = 0; tnd < 8; tnd++) {
      int drow = tnd * 16 + lm;
#pragma unroll
      for (int kv2 = 0; kv2 < 2; kv2++) {
        int ch = (kv2 * 4 + qd) ^ (drow & 7);
        b8 vfr = *(const b8*)&Vs[drow * 64 + ch * 8];
#pragma unroll
        for (int mt = 0; mt < 2; mt++)
          o[mt][tnd] = mfma_bf16(pa[mt][kv2], vfr, o[mt][tnd]);
      }
    }
    __builtin_amdgcn_s_setprio(0);
    __builtin_amdgcn_sched_barrier(0);  // keep next iter's stage below
    __builtin_amdgcn_s_barrier();       // all reads of buf cb done -> restageable
  }

  const int b = bh >> 3, h = bh & 7;
#pragma unroll
  for (int mt = 0; mt < 2; mt++) {
    float rinv[4];
#pragma unroll
    for (int r = 0; r < 4; r++) rinv[r] = 1.0f / lacc[mt][r];
#pragma unroll
    for (int tnd = 0; tnd < 8; tnd++) {
      int d = tnd * 16 + lm;
#pragma unroll
      for (int r = 0; r < 4; r++) {
        int sIdx = qt * 128 + w * 32 + mt * 16 + qd * 4 + r;
        O[((size_t)b * 1024 + sIdx) * 1024 + h * 128 + d] =
            __float2bfloat16(o[mt][tnd][r] * rinv[r]);
      }
    }
  }
}

// ---------------------------------------------------------------------------
// update v4: m = o @ W_pinv + b_pinv (rank-8), upd = m @ W_attn[l] + b_attn[l],
// cur += upd, curb = bf16(cur), curf8 = fp8(cur).
// Streamed to fit 64 VGPR with no scratch spills (R5 lesson: spills cost 80MB
// of HBM write-back). Coalesced chunks of 4: h(c) = c*256 + lane*4 (R4 lesson:
// contiguous-16-per-lane caused 4x write amplification).
// ---------------------------------------------------------------------------
__global__ __launch_bounds__(256, 4)
void update_kernel(const bf16* __restrict__ O, const float* __restrict__ Wpinv,
                   const float* __restrict__ bpinv, const float* __restrict__ Wattn,
                   const float* __restrict__ battn, float* __restrict__ cur,
                   bf16* __restrict__ curb, uint8_t* __restrict__ curf8) {
  const int t = threadIdx.x, w = t >> 6, lane = t & 63;
  const int r0 = blockIdx.x * 8 + w * 2;  // this wave: rows r0, r0+1
  const int hb = lane * 4;                // base within each 256-column chunk

  // ---- phase A (streamed): a = O-row . Wpinv partials over this lane's h ----
  float a0[8], a1[8];
#pragma unroll
  for (int j = 0; j < 8; j++) { a0[j] = 0.f; a1[j] = 0.f; }
#pragma unroll
  for (int c = 0; c < 4; c++) {
    const bf16* p0 = O + (size_t)r0 * 1024 + c * 256 + hb;
    bf16 t0[4], t1[4];
    *(ushort4*)t0 = *(const ushort4*)p0;
    *(ushort4*)t1 = *(const ushort4*)(p0 + 1024);
#pragma unroll
    for (int e = 0; e < 4; e++) {
      float v0 = __bfloat162float(t0[e]);
      float v1 = __bfloat162float(t1[e]);
      const float* wr = Wpinv + (size_t)(c * 256 + hb + e) * 8;
      float4 wa = *(const float4*)wr;
      float4 wb = *(const float4*)(wr + 4);
      a0[0] += v0 * wa.x; a0[1] += v0 * wa.y;
      a0[2] += v0 * wa.z; a0[3] += v0 * wa.w;
      a0[4] += v0 * wb.x; a0[5] += v0 * wb.y;
      a0[6] += v0 * wb.z; a0[7] += v0 * wb.w;
      a1[0] += v1 * wa.x; a1[1] += v1 * wa.y;
      a1[2] += v1 * wa.z; a1[3] += v1 * wa.w;
      a1[4] += v1 * wb.x; a1[5] += v1 * wb.y;
      a1[6] += v1 * wb.z; a1[7] += v1 * wb.w;
    }
  }
  // butterfly over the wave: every lane ends with the full sum
#pragma unroll
  for (int j = 0; j < 8; j++) {
#pragma unroll
    for (int off = 32; off; off >>= 1) {
      a0[j] += __shfl_xor(a0[j], off, 64);
      a1[j] += __shfl_xor(a1[j], off, 64);
    }
  }
#pragma unroll
  for (int j = 0; j < 8; j++) {
    float bp = bpinv[j];
    a0[j] += bp;   // a0/a1 now hold m0/m1
    a1[j] += bp;
  }

  // ---- phase B (streamed): per chunk, compute upd and retire immediately ----
#pragma unroll
  for (int c = 0; c < 4; c++) {
    float4 bv = *(const float4*)(battn + c * 256 + hb);
    float u00 = bv.x, u01 = bv.y, u02 = bv.z, u03 = bv.w;
    float u10 = bv.x, u11 = bv.y, u12 = bv.z, u13 = bv.w;
#pragma unroll
    for (int j = 0; j < 8; j++) {
      float4 wv = *(const float4*)(Wattn + (size_t)j * 1024 + c * 256 + hb);
      u00 += a0[j] * wv.x; u01 += a0[j] * wv.y;
      u02 += a0[j] * wv.z; u03 += a0[j] * wv.w;
      u10 += a1[j] * wv.x; u11 += a1[j] * wv.y;
      u12 += a1[j] * wv.z; u13 += a1[j] * wv.w;
    }
    // row r0
    {
      float* cp = cur + (size_t)r0 * 1024 + c * 256 + hb;
      float4 c4 = *(float4*)cp;
      c4.x += u00; c4.y += u01; c4.z += u02; c4.w += u03;
      *(float4*)cp = c4;
      bf16 cb[4];
      cb[0] = __float2bfloat16(c4.x); cb[1] = __float2bfloat16(c4.y);
      cb[2] = __float2bfloat16(c4.z); cb[3] = __float2bfloat16(c4.w);
      *(ushort4*)(curb + (size_t)r0 * 1024 + c * 256 + hb) = *(ushort4*)cb;
      uint32_t p = (uint32_t)to_fp8(c4.x) | ((uint32_t)to_fp8(c4.y) << 8) |
                   ((uint32_t)to_fp8(c4.z) << 16) | ((uint32_t)to_fp8(c4.w) << 24);
      *(uint32_t*)(curf8 + (size_t)r0 * 1024 + c * 256 + hb) = p;
    }
    // row r0+1
    {
      float* cp = cur + (size_t)(r0 + 1) * 1024 + c * 256 + hb;
      float4 c4 = *(float4*)cp;
      c4.x += u10; c4.y += u11; c4.z += u12; c4.w += u13;
      *(float4*)cp = c4;
      bf16 cb[4];
      cb[0] = __float2bfloat16(c4.x); cb[1] = __float2bfloat16(c4.y);
      cb[2] = __float2bfloat16(c4.z); cb[3] = __float2bfloat16(c4.w);
      *(ushort4*)(curb + (size_t)(r0 + 1) * 1024 + c * 256 + hb) = *(ushort4*)cb;
      uint32_t p = (uint32_t)to_fp8(c4.x) | ((uint32_t)to_fp8(c4.y) << 8) |
                   ((uint32_t)to_fp8(c4.z) << 16) | ((uint32_t)to_fp8(c4.w) << 24);
      *(uint32_t*)(curf8 + (size_t)(r0 + 1) * 1024 + c * 256 + hb) = p;
    }
  }
}

// ---------------------------------------------------------------------------
extern "C" void kernel_launch(void* const* d_in, const int* in_sizes, int n_in,
                              void* d_out, int out_size, void* d_ws, size_t ws_size,
                              hipStream_t stream) {
  const float* x      = (const float*)d_in[0];
  const float* W_qkv  = (const float*)d_in[1];
  const float* b_qkv  = (const float*)d_in[2];
  const float* W_pinv = (const float*)d_in[3];
  const float* b_pinv = (const float*)d_in[4];
  const float* W_attn = (const float*)d_in[5];
  const float* b_attn = (const float*)d_in[6];
  const float* W_out  = (const float*)d_in[7];
  const float* b_out  = (const float*)d_in[8];

  char* ws = (char*)d_ws;
  size_t off = 0;
  auto alloc = [&](size_t bytes) -> void* {
    void* p = ws + off;
    off += (bytes + 255) & ~(size_t)255;
    return p;
  };
  float* cur     = (float*)alloc((size_t)8192 * 1024 * 4);    // 32MB
  bf16* curb     = (bf16*)alloc((size_t)8192 * 1024 * 2);     // 16MB
  uint8_t* curf8 = (uint8_t*)alloc((size_t)8192 * 1024);      // 8MB
  uint8_t* Wqkv8 = (uint8_t*)alloc((size_t)3072 * 1024);      // 3MB [3072][1024] fp8
  bf16* Woutt    = (bf16*)alloc((size_t)1024 * 1024 * 2);     // 2MB
  bf16* Q        = (bf16*)alloc((size_t)8192 * 1024 * 2);     // 16MB [B,H,S,HD] flowed
  bf16* Kt       = (bf16*)alloc((size_t)8192 * 1024 * 2);     // 16MB [B,H,S,HD] flowed
  bf16* Vt       = (bf16*)alloc((size_t)8192 * 1024 * 2);     // 16MB [B,H,HD,S]
  bf16* O        = (bf16*)alloc((size_t)8192 * 1024 * 2);     // 16MB
  (void)ws_size; (void)in_sizes; (void)n_in; (void)out_size;

  prep_kernel<<<8192, 256, 0, stream>>>(x, cur, curb, curf8);
  transpose_cast_fp8<<<dim3(96, 32), 256, 0, stream>>>(W_qkv, Wqkv8, 1024, 3072);
  transpose_cast<<<dim3(32, 32), 256, 0, stream>>>(W_out, Woutt, 1024, 1024);

  for (int l = 0; l < 3; l++) {
    gemm_qkv_fp8<<<dim3(64, 24), 256, 0, stream>>>(curf8, Wqkv8, b_qkv, Q, Kt, Vt,
                                                   8192, 3072, 1024);
    attn_kernel<<<dim3(64, 8), 256, 0, stream>>>(Q, Kt, Vt, O);
    update_kernel<<<1024, 256, 0, stream>>>(O, W_pinv, b_pinv,
                                            W_attn + (size_t)l * 8 * 1024,
                                            b_attn + (size_t)l * 1024, cur, curb,
                                            curf8);
  }
  gemm_bt<<<dim3(64, 8), 256, 0, stream>>>(curb, Woutt, b_out, (float*)d_out, 8192,
                                           1024, 1024);
}

// Round 9
// 450.710 us; speedup vs baseline: 1.6235x; 1.1164x over previous
//
#include <hip/hip_runtime.h>
#include <hip/hip_bf16.h>
#include <hip/hip_fp8.h>
#include <cstdint>

typedef __hip_bfloat16 bf16;
typedef __bf16 b8 __attribute__((ext_vector_type(8)));
typedef float f4v __attribute__((ext_vector_type(4)));
typedef short s8v __attribute__((ext_vector_type(8)));
typedef int i8v __attribute__((ext_vector_type(8)));

#define DEVI static __device__ __forceinline__

// async global->LDS, 16B per lane. LDS dest is wave-uniform base + lane*16.
DEVI void gload16(const void* g, void* l) {
  __builtin_amdgcn_global_load_lds(
      (const __attribute__((address_space(1))) void*)(uintptr_t)g,
      (__attribute__((address_space(3))) void*)(uint32_t)(uintptr_t)l,
      16, 0, 0);
}

DEVI f4v mfma_bf16(b8 a, b8 b, f4v c) {
  return __builtin_amdgcn_mfma_f32_16x16x32_bf16(a, b, c, 0, 0, 0);
}

// MX-scaled fp8 (OCP e4m3), K=128, unit scales (E8M0 127 = 2^0 in every byte).
DEVI f4v mfma_fp8(i8v a, i8v b, f4v c) {
  return __builtin_amdgcn_mfma_scale_f32_16x16x128_f8f6f4(
      a, b, c, 0, 0, 0, 0x7F7F7F7F, 0, 0x7F7F7F7F);
}

DEVI uint8_t to_fp8(float f) {
  __hip_fp8_e4m3 v(f);
  return v.__x;
}

// ---------------------------------------------------------------------------
// prep: x -> cur (fp32) + curb (bf16) + curf8 (fp8 e4m3)
// ---------------------------------------------------------------------------
__global__ void prep_kernel(const float* __restrict__ x, float* __restrict__ cur,
                            bf16* __restrict__ curb, uint8_t* __restrict__ curf8) {
  int i = (blockIdx.x * 256 + threadIdx.x) * 4;
  float4 v = *(const float4*)(x + i);
  *(float4*)(cur + i) = v;
  __hip_bfloat162 a, b;
  a.x = __float2bfloat16(v.x); a.y = __float2bfloat16(v.y);
  b.x = __float2bfloat16(v.z); b.y = __float2bfloat16(v.w);
  *(__hip_bfloat162*)(curb + i) = a;
  *(__hip_bfloat162*)(curb + i + 2) = b;
  uint32_t p = (uint32_t)to_fp8(v.x) | ((uint32_t)to_fp8(v.y) << 8) |
               ((uint32_t)to_fp8(v.z) << 16) | ((uint32_t)to_fp8(v.w) << 24);
  *(uint32_t*)(curf8 + i) = p;
}

// ---------------------------------------------------------------------------
// transpose + cast fp32 [R][C] -> bf16 [C][R]   (weights, tiny)
// ---------------------------------------------------------------------------
__global__ void transpose_cast(const float* __restrict__ in, bf16* __restrict__ out,
                               int R, int C) {
  __shared__ float tile[32][33];
  int c0 = blockIdx.x * 32, r0 = blockIdx.y * 32;
  int tx = threadIdx.x & 31, ty = threadIdx.x >> 5;  // 32 x 8
  for (int rr = ty; rr < 32; rr += 8)
    tile[rr][tx] = in[(size_t)(r0 + rr) * C + c0 + tx];
  __syncthreads();
  for (int cc = ty; cc < 32; cc += 8)
    out[(size_t)(c0 + cc) * R + r0 + tx] = __float2bfloat16(tile[tx][cc]);
}

// transpose + cast fp32 [R][C] -> fp8 [C][R]
__global__ void transpose_cast_fp8(const float* __restrict__ in,
                                   uint8_t* __restrict__ out, int R, int C) {
  __shared__ float tile[32][33];
  int c0 = blockIdx.x * 32, r0 = blockIdx.y * 32;
  int tx = threadIdx.x & 31, ty = threadIdx.x >> 5;
  for (int rr = ty; rr < 32; rr += 8)
    tile[rr][tx] = in[(size_t)(r0 + rr) * C + c0 + tx];
  __syncthreads();
  for (int cc = ty; cc < 32; cc += 8)
    out[(size_t)(c0 + cc) * R + r0 + tx] = to_fp8(tile[tx][cc]);
}

// ---------------------------------------------------------------------------
// QKV GEMM, MX-fp8: C[M,N] = A[M,K](fp8,rm) @ Bt[N,K](fp8,rm)^T + bias
// 128x128 tile, BK=128 (32KB LDS -> 3 blocks/CU), 16x16x128 scaled MFMA.
// At ~1030 TF-equiv this sits AT the m97-structure MX-fp8 ceiling (m145: 995);
// only an 8-phase 256-tile rewrite moves it further. T5 setprio added: 3
// blocks/CU run at independent phases, so the CU scheduler can favor the
// MFMA-cluster wave over other blocks' staging.
// ---------------------------------------------------------------------------
__global__ __launch_bounds__(256, 3)
void gemm_qkv_fp8(const uint8_t* __restrict__ A, const uint8_t* __restrict__ Bt,
                  const float* __restrict__ bias, bf16* __restrict__ Qo,
                  bf16* __restrict__ Ko, bf16* __restrict__ Vto, int M, int N,
                  int K) {
  __shared__ uint8_t As[128 * 128];
  __shared__ uint8_t Bs[128 * 128];
  __shared__ float red[2][128];
  const int t = threadIdx.x;
  const int w = t >> 6, lane = t & 63;
  const int lm = lane & 15, qd = lane >> 4;
  const int m0 = blockIdx.x * 128, n0 = blockIdx.y * 128;
  const int wm = (w & 1) * 64, wn = (w >> 1) * 64;

  const uint8_t* Ag = A + (size_t)m0 * K;
  const uint8_t* Bg = Bt + (size_t)n0 * K;

  f4v acc[4][4];
  f4v zero = {0.f, 0.f, 0.f, 0.f};
#pragma unroll
  for (int i = 0; i < 4; i++)
#pragma unroll
    for (int j = 0; j < 4; j++) acc[i][j] = zero;

  for (int k0 = 0; k0 < K; k0 += 128) {
#pragma unroll
    for (int c = 0; c < 4; c++) {
      int s = c * 256 + t;
      int r = s >> 3;
      int kc = (s & 7) ^ (r & 7);  // xor-swizzle 16B chunks within the 128B row
      gload16(Ag + (size_t)r * K + k0 + kc * 16, &As[s * 16]);
      gload16(Bg + (size_t)r * K + k0 + kc * 16, &Bs[s * 16]);
    }
    __syncthreads();
    i8v af[4], bfr[4];
#pragma unroll
    for (int tm = 0; tm < 4; tm++) {
      int row = wm + tm * 16 + lm;
      int ch = (qd * 2) ^ (row & 7);          // lane's 32B = chunks ch, ch^1
      union { int4 q[2]; i8v v; } u;
      u.q[0] = *(const int4*)&As[row * 128 + ch * 16];
      u.q[1] = *(const int4*)&As[row * 128 + (ch ^ 1) * 16];
      af[tm] = u.v;
    }
#pragma unroll
    for (int tn = 0; tn < 4; tn++) {
      int row = wn + tn * 16 + lm;
      int ch = (qd * 2) ^ (row & 7);
      union { int4 q[2]; i8v v; } u;
      u.q[0] = *(const int4*)&Bs[row * 128 + ch * 16];
      u.q[1] = *(const int4*)&Bs[row * 128 + (ch ^ 1) * 16];
      bfr[tn] = u.v;
    }
    __builtin_amdgcn_s_setprio(1);
#pragma unroll
    for (int tm = 0; tm < 4; tm++)
#pragma unroll
      for (int tn = 0; tn < 4; tn++)
        acc[tm][tn] = mfma_fp8(af[tm], bfr[tn], acc[tm][tn]);
    __builtin_amdgcn_s_setprio(0);
    __syncthreads();
  }

  const int part = n0 >> 10;  // block-uniform: 0=Q, 1=K, 2=V
  const int hh = (n0 >> 7) & 7;
  if (part == 2) {
#pragma unroll
    for (int tm = 0; tm < 4; tm++)
#pragma unroll
      for (int tn = 0; tn < 4; tn++) {
        int d = wn + tn * 16 + lm;
        float bv = bias[n0 + d];
        int row0 = m0 + wm + tm * 16 + qd * 4;
        int b = row0 >> 10, s0 = row0 & 1023;
        bf16 vt[4];
#pragma unroll
        for (int r = 0; r < 4; r++) vt[r] = __float2bfloat16(acc[tm][tn][r] + bv);
        *(ushort4*)&Vto[((size_t)(b * 8 + hh)) * 131072 + (size_t)d * 1024 + s0] =
            *(ushort4*)vt;
      }
  } else {
    float bvs[4];
#pragma unroll
    for (int tn = 0; tn < 4; tn++) bvs[tn] = bias[n0 + wn + tn * 16 + lm];
    float ss[4][4];
#pragma unroll
    for (int tm = 0; tm < 4; tm++)
#pragma unroll
      for (int r = 0; r < 4; r++) {
        float s = 0.f;
#pragma unroll
        for (int tn = 0; tn < 4; tn++) {
          float v = acc[tm][tn][r] + bvs[tn];
          s += v * v;
        }
#pragma unroll
        for (int off = 1; off < 16; off <<= 1) s += __shfl_xor(s, off, 64);
        ss[tm][r] = s;
      }
    if (lm == 0) {
#pragma unroll
      for (int tm = 0; tm < 4; tm++)
#pragma unroll
        for (int r = 0; r < 4; r++)
          red[w >> 1][wm + tm * 16 + qd * 4 + r] = ss[tm][r];
    }
    __syncthreads();
    const float qsc = (part == 0) ? 0.08838834764831845f : 1.0f;  // 1/sqrt(128)
    float scr[4][4];
#pragma unroll
    for (int tm = 0; tm < 4; tm++)
#pragma unroll
      for (int r = 0; r < 4; r++) {
        int row = wm + tm * 16 + qd * 4 + r;
        float tot = red[0][row] + red[1][row];
        float nrm = fmaxf(sqrtf(tot), 1e-7f);
        scr[tm][r] = tanhf(nrm) / nrm * qsc;
      }
    bf16* dst = (part == 0) ? Qo : Ko;
#pragma unroll
    for (int tm = 0; tm < 4; tm++)
#pragma unroll
      for (int tn = 0; tn < 4; tn++) {
        int d = wn + tn * 16 + lm;
        int row0 = m0 + wm + tm * 16 + qd * 4;
        int b = row0 >> 10, s0 = row0 & 1023;
#pragma unroll
        for (int r = 0; r < 4; r++)
          dst[(((size_t)(b * 8 + hh)) * 1024 + s0 + r) * 128 + d] =
              __float2bfloat16((acc[tm][tn][r] + bvs[tn]) * scr[tm][r]);
      }
  }
}

// ---------------------------------------------------------------------------
// GEMM (bf16): C[M,N] = A[M,K] @ Bt[N,K]^T + bias, fp32 out. (final projection)
// T5 setprio around the MFMA cluster (3 blocks/CU, independent phases).
// ---------------------------------------------------------------------------
__global__ __launch_bounds__(256, 3)
void gemm_bt(const bf16* __restrict__ A, const bf16* __restrict__ Bt,
             const float* __restrict__ bias, float* __restrict__ Cf, int M, int N,
             int K) {
  __shared__ bf16 As[128 * 64];
  __shared__ bf16 Bs[128 * 64];
  const int t = threadIdx.x;
  const int w = t >> 6, lane = t & 63;
  const int lm = lane & 15, qd = lane >> 4;
  const int m0 = blockIdx.x * 128, n0 = blockIdx.y * 128;
  const int wm = (w & 1) * 64, wn = (w >> 1) * 64;

  const bf16* Ag = A + (size_t)m0 * K;
  const bf16* Bg = Bt + (size_t)n0 * K;

  f4v acc[4][4];
  f4v zero = {0.f, 0.f, 0.f, 0.f};
#pragma unroll
  for (int i = 0; i < 4; i++)
#pragma unroll
    for (int j = 0; j < 4; j++) acc[i][j] = zero;

  for (int k0 = 0; k0 < K; k0 += 64) {
#pragma unroll
    for (int c = 0; c < 4; c++) {
      int s = c * 256 + t;
      int r = s >> 3;
      int kc = (s & 7) ^ (r & 7);
      gload16(Ag + (size_t)r * K + k0 + kc * 8, &As[s * 8]);
      gload16(Bg + (size_t)r * K + k0 + kc * 8, &Bs[s * 8]);
    }
    __syncthreads();
#pragma unroll
    for (int ks = 0; ks < 2; ks++) {
      b8 af[4], bfr[4];
#pragma unroll
      for (int tm = 0; tm < 4; tm++) {
        int row = wm + tm * 16 + lm;
        int ch = (ks * 4 + qd) ^ (row & 7);
        af[tm] = *(const b8*)&As[row * 64 + ch * 8];
      }
#pragma unroll
      for (int tn = 0; tn < 4; tn++) {
        int row = wn + tn * 16 + lm;
        int ch = (ks * 4 + qd) ^ (row & 7);
        bfr[tn] = *(const b8*)&Bs[row * 64 + ch * 8];
      }
      __builtin_amdgcn_s_setprio(1);
#pragma unroll
      for (int tm = 0; tm < 4; tm++)
#pragma unroll
        for (int tn = 0; tn < 4; tn++)
          acc[tm][tn] = mfma_bf16(af[tm], bfr[tn], acc[tm][tn]);
      __builtin_amdgcn_s_setprio(0);
    }
    __syncthreads();
  }

#pragma unroll
  for (int tm = 0; tm < 4; tm++)
#pragma unroll
    for (int tn = 0; tn < 4; tn++) {
      int col = n0 + wn + tn * 16 + lm;
      float bv = bias[col];
#pragma unroll
      for (int r = 0; r < 4; r++) {
        int row = m0 + wm + tm * 16 + qd * 4 + r;
        Cf[(size_t)row * N + col] = acc[tm][tn][r] + bv;
      }
    }
}

// ---------------------------------------------------------------------------
// Flash attention + FUSED update-phase-A. No-max softmax; l via MFMA vs ones.
// K/V double-buffered (80KB), counted vmcnt(8) + raw s_barrier, T5 setprio.
// NEW (R9): O is never materialized. The epilogue computes the per-head
// partial manifold projection m_j(q) = sum_d (o[q][d]/l) * Wpinv[h*128+d][j]
// (512 FMA + 256 shfl, one-time) and writes Mpart[bh][s][8] (2MB) -- each
// (bh,s) has exactly one writer, no atomics. Saves 32MB/layer of O traffic
// and update's whole reduction phase.
// ---------------------------------------------------------------------------
__global__ __launch_bounds__(256, 2)
void attn_kernel(const bf16* __restrict__ Qf, const bf16* __restrict__ Kf,
                 const bf16* __restrict__ Vt, const float* __restrict__ Wpinv,
                 float* __restrict__ Mpart) {
  __shared__ bf16 smem[40960];            // 81920 B = 2x(K 8192 + V 8192) + P 8192
  bf16* Ps = smem + 32768;                // [4 waves][32 q][64 s'] perm-swizzled
  const int t = threadIdx.x, w = t >> 6, lane = t & 63;
  const int lm = lane & 15, qd = lane >> 4;
  const int bh = blockIdx.x, qt = blockIdx.y;
  const bf16* Qg = Qf + ((size_t)bh * 1024 + qt * 128) * 128;
  const bf16* Kg = Kf + (size_t)bh * 131072;
  const bf16* Vg = Vt + (size_t)bh * 131072;
  bf16* Pw = Ps + w * 2048;

  // stage K/V tile kt into buffer b (8 gload_lds per thread)
  auto stage = [&](int kt, int b) {
    bf16* Ksb = smem + b * 16384;
    bf16* Vsb = Ksb + 8192;
#pragma unroll
    for (int c = 0; c < 4; c++) {
      int s = c * 256 + t;
      int r = s >> 4;
      int kc = (s & 15) ^ (r & 7);
      gload16(Kg + (size_t)(kt * 64 + r) * 128 + kc * 8, &Ksb[s * 8]);
      int rv = s >> 3;
      int kv = (s & 7) ^ (rv & 7);
      gload16(Vg + (size_t)rv * 1024 + kt * 64 + kv * 8, &Vsb[s * 8]);
    }
  };

  b8 qfr[2][4];
#pragma unroll
  for (int mt = 0; mt < 2; mt++)
#pragma unroll
    for (int ks = 0; ks < 4; ks++)
      qfr[mt][ks] =
          *(const b8*)(Qg + (size_t)(w * 32 + mt * 16 + lm) * 128 + ks * 32 + qd * 8);

  f4v o[2][8];
  f4v lacc[2];
  f4v zero = {0.f, 0.f, 0.f, 0.f};
#pragma unroll
  for (int mt = 0; mt < 2; mt++) {
    lacc[mt] = zero;
#pragma unroll
    for (int i = 0; i < 8; i++) o[mt][i] = zero;
  }
  union { s8v s; b8 b; } uo;
#pragma unroll
  for (int i = 0; i < 8; i++) uo.s[i] = 0x3F80;  // bf16 1.0
  const b8 ones = uo.b;

  stage(0, 0);
  for (int kt = 0; kt < 16; kt++) {
    const int cb = kt & 1;
    if (kt < 15) {
      stage(kt + 1, cb ^ 1);                         // prefetch next tile
      asm volatile("s_waitcnt vmcnt(8)" ::: "memory");  // wait current tile only
    } else {
      asm volatile("s_waitcnt vmcnt(0)" ::: "memory");
    }
    __builtin_amdgcn_sched_barrier(0);
    __builtin_amdgcn_s_barrier();       // all threads' current-tile DMA landed
    __builtin_amdgcn_sched_barrier(0);  // pin ds_reads below the barrier
    const bf16* Ks = smem + cb * 16384;
    const bf16* Vs = Ks + 8192;

    // scores: K frags read ONCE, used by both m-tiles
    f4v sc[2][4];
#pragma unroll
    for (int mt = 0; mt < 2; mt++)
#pragma unroll
      for (int tn = 0; tn < 4; tn++) sc[mt][tn] = zero;
    __builtin_amdgcn_s_setprio(1);
#pragma unroll
    for (int tn = 0; tn < 4; tn++) {
      int krow = tn * 16 + lm;
#pragma unroll
      for (int ks = 0; ks < 4; ks++) {
        int ch = (ks * 4 + qd) ^ (krow & 7);
        b8 kfr = *(const b8*)&Ks[krow * 128 + ch * 8];
        sc[0][tn] = mfma_bf16(qfr[0][ks], kfr, sc[0][tn]);
        sc[1][tn] = mfma_bf16(qfr[1][ks], kfr, sc[1][tn]);
      }
    }
    __builtin_amdgcn_s_setprio(0);
    // P = exp(s) -> LDS (perm swizzle (q>>1)&7)
#pragma unroll
    for (int mt = 0; mt < 2; mt++)
#pragma unroll
      for (int tn = 0; tn < 4; tn++)
#pragma unroll
        for (int r = 0; r < 4; r++) {
          int qi = mt * 16 + qd * 4 + r;
          int ch = (tn * 2 + (lm >> 3)) ^ ((qi >> 1) & 7);
          Pw[qi * 64 + ch * 8 + (lm & 7)] = __float2bfloat16(__expf(sc[mt][tn][r]));
        }

    b8 pa[2][2];
#pragma unroll
    for (int mt = 0; mt < 2; mt++)
#pragma unroll
      for (int kv2 = 0; kv2 < 2; kv2++) {
        int qi = mt * 16 + lm;
        int ch = (kv2 * 4 + qd) ^ ((lm >> 1) & 7);
        pa[mt][kv2] = *(const b8*)&Pw[qi * 64 + ch * 8];
      }
    __builtin_amdgcn_s_setprio(1);
#pragma unroll
    for (int mt = 0; mt < 2; mt++)
#pragma unroll
      for (int kv2 = 0; kv2 < 2; kv2++)
        lacc[mt] = mfma_bf16(pa[mt][kv2], ones, lacc[mt]);
#pragma unroll
    for (int tnd = 0; tnd < 8; tnd++) {
      int drow = tnd * 16 + lm;
#pragma unroll
      for (int kv2 = 0; kv2 < 2; kv2++) {
        int ch = (kv2 * 4 + qd) ^ (drow & 7);
        b8 vfr = *(const b8*)&Vs[drow * 64 + ch * 8];
#pragma unroll
        for (int mt = 0; mt < 2; mt++)
          o[mt][tnd] = mfma_bf16(pa[mt][kv2], vfr, o[mt][tnd]);
      }
    }
    __builtin_amdgcn_s_setprio(0);
    __builtin_amdgcn_sched_barrier(0);  // keep next iter's stage below
    __builtin_amdgcn_s_barrier();       // all reads of buf cb done -> restageable
  }

  // ---- fused epilogue: per-head partial m -> Mpart (no O materialized) ----
  const int h = bh & 7;
  // this lane's 8 Wpinv rows: d = tnd*16 + lm
  float wp[8][8];
#pragma unroll
  for (int tnd = 0; tnd < 8; tnd++) {
    const float* wr = Wpinv + (size_t)(h * 128 + tnd * 16 + lm) * 8;
    float4 wa = *(const float4*)wr;
    float4 wb = *(const float4*)(wr + 4);
    wp[tnd][0] = wa.x; wp[tnd][1] = wa.y; wp[tnd][2] = wa.z; wp[tnd][3] = wa.w;
    wp[tnd][4] = wb.x; wp[tnd][5] = wb.y; wp[tnd][6] = wb.z; wp[tnd][7] = wb.w;
  }
#pragma unroll
  for (int mt = 0; mt < 2; mt++) {
    float rinv[4];
#pragma unroll
    for (int r = 0; r < 4; r++) rinv[r] = 1.0f / lacc[mt][r];
#pragma unroll
    for (int r = 0; r < 4; r++) {
      float pm[8];
#pragma unroll
      for (int j = 0; j < 8; j++) pm[j] = 0.f;
#pragma unroll
      for (int tnd = 0; tnd < 8; tnd++) {
        float ov = o[mt][tnd][r] * rinv[r];
#pragma unroll
        for (int j = 0; j < 8; j++) pm[j] += ov * wp[tnd][j];
      }
      // reduce over the 16 lm lanes (d dimension)
#pragma unroll
      for (int j = 0; j < 8; j++) {
#pragma unroll
        for (int off = 1; off < 16; off <<= 1)
          pm[j] += __shfl_xor(pm[j], off, 64);
      }
      // lane lm==j stores m_j (compile-time-indexed select chain, rule #20)
      float sv = pm[0];
#pragma unroll
      for (int j = 1; j < 8; j++) sv = (lm == j) ? pm[j] : sv;
      if (lm < 8) {
        int sIdx = qt * 128 + w * 32 + mt * 16 + qd * 4 + r;
        Mpart[((size_t)bh * 1024 + sIdx) * 8 + lm] = sv;
      }
    }
  }
}

// ---------------------------------------------------------------------------
// update v5: m = sum_h Mpart[b,h,s] + b_pinv; upd = m @ W_attn[l] + b_attn[l];
// cur += upd; curb = bf16(cur); curf8 = fp8(cur).
// Phase A is now a 64-float gather + shfl reduce (O and its reduction gone --
// fused into attn). Phase B unchanged (streamed chunks of 4, coalesced,
// no spills -- R4/R5 lessons).
// ---------------------------------------------------------------------------
__global__ __launch_bounds__(256, 4)
void update_kernel(const float* __restrict__ Mpart, const float* __restrict__ bpinv,
                   const float* __restrict__ Wattn, const float* __restrict__ battn,
                   float* __restrict__ cur, bf16* __restrict__ curb,
                   uint8_t* __restrict__ curf8) {
  const int t = threadIdx.x, w = t >> 6, lane = t & 63;
  const int r0 = blockIdx.x * 8 + w * 2;  // this wave: rows r0, r0+1
  const int hb = lane * 4;                // base within each 256-column chunk
  const int hh = lane >> 3, jj = lane & 7;

  // ---- phase A: m[j] = bpinv[j] + sum_h Mpart[((b*8+h)*1024+s)*8+j] ----
  float a0[8], a1[8];
  {
    const int b0 = r0 >> 10, s0 = r0 & 1023;
    float v0 = Mpart[(((size_t)b0 * 8 + hh) * 1024 + s0) * 8 + jj];
    float v1 = Mpart[(((size_t)b0 * 8 + hh) * 1024 + s0 + 1) * 8 + jj];
#pragma unroll
    for (int off = 8; off < 64; off <<= 1) {
      v0 += __shfl_xor(v0, off, 64);
      v1 += __shfl_xor(v1, off, 64);
    }
    // lane j (0..7) now holds the h-sum for component j; broadcast all 8
#pragma unroll
    for (int j = 0; j < 8; j++) {
      float bp = bpinv[j];
      a0[j] = __shfl(v0, j, 64) + bp;
      a1[j] = __shfl(v1, j, 64) + bp;
    }
  }

  // ---- phase B (streamed): per chunk, compute upd and retire immediately ----
#pragma unroll
  for (int c = 0; c < 4; c++) {
    float4 bv = *(const float4*)(battn + c * 256 + hb);
    float u00 = bv.x, u01 = bv.y, u02 = bv.z, u03 = bv.w;
    float u10 = bv.x, u11 = bv.y, u12 = bv.z, u13 = bv.w;
#pragma unroll
    for (int j = 0; j < 8; j++) {
      float4 wv = *(const float4*)(Wattn + (size_t)j * 1024 + c * 256 + hb);
      u00 += a0[j] * wv.x; u01 += a0[j] * wv.y;
      u02 += a0[j] * wv.z; u03 += a0[j] * wv.w;
      u10 += a1[j] * wv.x; u11 += a1[j] * wv.y;
      u12 += a1[j] * wv.z; u13 += a1[j] * wv.w;
    }
    // row r0
    {
      float* cp = cur + (size_t)r0 * 1024 + c * 256 + hb;
      float4 c4 = *(float4*)cp;
      c4.x += u00; c4.y += u01; c4.z += u02; c4.w += u03;
      *(float4*)cp = c4;
      bf16 cb[4];
      cb[0] = __float2bfloat16(c4.x); cb[1] = __float2bfloat16(c4.y);
      cb[2] = __float2bfloat16(c4.z); cb[3] = __float2bfloat16(c4.w);
      *(ushort4*)(curb + (size_t)r0 * 1024 + c * 256 + hb) = *(ushort4*)cb;
      uint32_t p = (uint32_t)to_fp8(c4.x) | ((uint32_t)to_fp8(c4.y) << 8) |
                   ((uint32_t)to_fp8(c4.z) << 16) | ((uint32_t)to_fp8(c4.w) << 24);
      *(uint32_t*)(curf8 + (size_t)r0 * 1024 + c * 256 + hb) = p;
    }
    // row r0+1
    {
      float* cp = cur + (size_t)(r0 + 1) * 1024 + c * 256 + hb;
      float4 c4 = *(float4*)cp;
      c4.x += u10; c4.y += u11; c4.z += u12; c4.w += u13;
      *(float4*)cp = c4;
      bf16 cb[4];
      cb[0] = __float2bfloat16(c4.x); cb[1] = __float2bfloat16(c4.y);
      cb[2] = __float2bfloat16(c4.z); cb[3] = __float2bfloat16(c4.w);
      *(ushort4*)(curb + (size_t)(r0 + 1) * 1024 + c * 256 + hb) = *(ushort4*)cb;
      uint32_t p = (uint32_t)to_fp8(c4.x) | ((uint32_t)to_fp8(c4.y) << 8) |
                   ((uint32_t)to_fp8(c4.z) << 16) | ((uint32_t)to_fp8(c4.w) << 24);
      *(uint32_t*)(curf8 + (size_t)(r0 + 1) * 1024 + c * 256 + hb) = p;
    }
  }
}

// ---------------------------------------------------------------------------
extern "C" void kernel_launch(void* const* d_in, const int* in_sizes, int n_in,
                              void* d_out, int out_size, void* d_ws, size_t ws_size,
                              hipStream_t stream) {
  const float* x      = (const float*)d_in[0];
  const float* W_qkv  = (const float*)d_in[1];
  const float* b_qkv  = (const float*)d_in[2];
  const float* W_pinv = (const float*)d_in[3];
  const float* b_pinv = (const float*)d_in[4];
  const float* W_attn = (const float*)d_in[5];
  const float* b_attn = (const float*)d_in[6];
  const float* W_out  = (const float*)d_in[7];
  const float* b_out  = (const float*)d_in[8];

  char* ws = (char*)d_ws;
  size_t off = 0;
  auto alloc = [&](size_t bytes) -> void* {
    void* p = ws + off;
    off += (bytes + 255) & ~(size_t)255;
    return p;
  };
  float* cur     = (float*)alloc((size_t)8192 * 1024 * 4);    // 32MB
  bf16* curb     = (bf16*)alloc((size_t)8192 * 1024 * 2);     // 16MB
  uint8_t* curf8 = (uint8_t*)alloc((size_t)8192 * 1024);      // 8MB
  uint8_t* Wqkv8 = (uint8_t*)alloc((size_t)3072 * 1024);      // 3MB [3072][1024] fp8
  bf16* Woutt    = (bf16*)alloc((size_t)1024 * 1024 * 2);     // 2MB
  bf16* Q        = (bf16*)alloc((size_t)8192 * 1024 * 2);     // 16MB [B,H,S,HD] flowed
  bf16* Kt       = (bf16*)alloc((size_t)8192 * 1024 * 2);     // 16MB [B,H,S,HD] flowed
  bf16* Vt       = (bf16*)alloc((size_t)8192 * 1024 * 2);     // 16MB [B,H,HD,S]
  float* Mpart   = (float*)alloc((size_t)65536 * 8 * 4);      // 2MB [bh][s][8]
  (void)ws_size; (void)in_sizes; (void)n_in; (void)out_size;

  prep_kernel<<<8192, 256, 0, stream>>>(x, cur, curb, curf8);
  transpose_cast_fp8<<<dim3(96, 32), 256, 0, stream>>>(W_qkv, Wqkv8, 1024, 3072);
  transpose_cast<<<dim3(32, 32), 256, 0, stream>>>(W_out, Woutt, 1024, 1024);

  for (int l = 0; l < 3; l++) {
    gemm_qkv_fp8<<<dim3(64, 24), 256, 0, stream>>>(curf8, Wqkv8, b_qkv, Q, Kt, Vt,
                                                   8192, 3072, 1024);
    attn_kernel<<<dim3(64, 8), 256, 0, stream>>>(Q, Kt, Vt, W_pinv, Mpart);
    update_kernel<<<1024, 256, 0, stream>>>(Mpart, b_pinv,
                                            W_attn + (size_t)l * 8 * 1024,
                                            b_attn + (size_t)l * 1024, cur, curb,
                                            curf8);
  }
  gemm_bt<<<dim3(64, 8), 256, 0, stream>>>(curb, Woutt, b_out, (float*)d_out, 8192,
                                           1024, 1024);
}